// Round 3
// 1576.577 us; speedup vs baseline: 1.1660x; 1.1660x over previous
//
#include <hip/hip_runtime.h>

typedef unsigned short u16;
typedef unsigned int   u32;
typedef _Float16       f16;
typedef f16   f16x2  __attribute__((ext_vector_type(2)));
typedef f16   f16x8  __attribute__((ext_vector_type(8)));
typedef float f32x4  __attribute__((ext_vector_type(4)));
typedef u32   u32x2  __attribute__((ext_vector_type(2)));
typedef u32   u32x4  __attribute__((ext_vector_type(4)));

#define MDIM 8192
#define KDIM 4096
#define NDIM 11008
#define NKT  64    // K / 64
#define LDA  72    // padded A row stride in u16: 64 k + 8 pad; row*144B keeps 16B align, banks 2-way-free

__global__ __launch_bounds__(256) void int4_gemm(
    const float* __restrict__ x,     // [M][K] f32 (harness materializes fp16 as f32)
    const int*   __restrict__ wpk,   // [K/2][N] packed nibbles (low = even k, high = odd k)
    const float* __restrict__ sc,    // [K/128][N] f32
    const float* __restrict__ bias,  // [N] f32
    float*       __restrict__ out)   // [M][N] f32
{
    __shared__ __align__(16) u16 ldsA[128 * LDA];  // 18 KB, padded row-major [m][k] fp16
    __shared__ __align__(16) u16 ldsB[8192];       // 16 KB, fragment-ordered:
                                                   //   chunk = ks*512 + quad*128 + n -> 8 fp16 (8 consecutive k)

    const int tid  = threadIdx.x;
    const int wave = tid >> 6;
    const int lane = tid & 63;
    const int wm   = wave >> 1;          // 2x2 wave grid; each wave owns 64x64 of the 128x128 tile
    const int wn   = wave & 1;
    const int quad = lane >> 4;
    const int l15  = lane & 15;
    const int m0   = blockIdx.y * 128;
    const int n0   = blockIdx.x * 128;

    // B staging: thread -> one column n, 16 packed rows (k = half*32 .. half*32+31 of the tile)
    const int n_local = tid & 127;
    const int half    = tid >> 7;
    const int gn      = n0 + n_local;

    f32x4 acc[4][4];
    const f32x4 zero4 = {0.f, 0.f, 0.f, 0.f};
#pragma unroll
    for (int mt = 0; mt < 4; ++mt)
#pragma unroll
        for (int nt = 0; nt < 4; ++nt) acc[mt][nt] = zero4;

    // ---- prefetch tile 0 ----
    // A: 8 passes; pass p: chunk id c = p*256+tid, row = c>>4 (0..127), kchunk = c&15 (4 f32 each)
    f32x4 areg[8];
    int   pw[16];
    float scur;
    {
#pragma unroll
        for (int p = 0; p < 8; ++p) {
            const int c = p * 256 + tid;
            areg[p] = *(const f32x4*)(x + (size_t)(m0 + (c >> 4)) * KDIM + (c & 15) * 4);
        }
        const int kp0 = half * 16;
#pragma unroll
        for (int i = 0; i < 16; ++i) pw[i] = wpk[(kp0 + i) * NDIM + gn];
        scur = sc[gn];
    }

    for (int kt = 0; kt < NKT; ++kt) {
        // ---- dequant packed W regs -> ldsB (fragment order, fp16) ----
        // fp16 magic: 0x6400|q == 1024+q (exact). (1024+q) - 1032 == q-8 (EXACT fp16
        // subtraction, small integers). Then (q-8)*s is one v_pk_mul_f16, single
        // rounding -> bit-identical to reference's fp16 dequant. No fma needed.
        {
            const f16 sh = (f16)scur;
            const f16x2 s2 = {sh, sh};
            const f16x2 cm = {(f16)(-1032.0f), (f16)(-1032.0f)};
#pragma unroll
            for (int q = 0; q < 4; ++q) {
                u32 wds[4];
#pragma unroll
                for (int r = 0; r < 4; ++r) {
                    const u32 w = (u32)pw[q * 4 + r];
                    const u32 hbits = 0x64006400u | (w & 15u) | ((w & 0xF0u) << 12);
                    const f16x2 hv = __builtin_bit_cast(f16x2, hbits);
                    const f16x2 rr = (hv + cm) * s2;   // pk_add (exact) + pk_mul
                    wds[r] = __builtin_bit_cast(u32, rr);
                }
                u32x4 wv = {wds[0], wds[1], wds[2], wds[3]};
                *(u32x4*)&ldsB[(half * 512 + q * 128 + n_local) * 8] = wv;
            }
        }

        // ---- A regs: f32x4 -> packed fp16 via cvt_pkrtz (exact: x is exactly-fp16) ----
#pragma unroll
        for (int p = 0; p < 8; ++p) {
            const int c   = p * 256 + tid;
            const int row = c >> 4;
            const int kc  = c & 15;
            u32x2 v;
            v.x = __builtin_bit_cast(u32, __builtin_amdgcn_cvt_pkrtz(areg[p][0], areg[p][1]));
            v.y = __builtin_bit_cast(u32, __builtin_amdgcn_cvt_pkrtz(areg[p][2], areg[p][3]));
            *(u32x2*)&ldsA[row * LDA + kc * 4] = v;
        }

        __syncthreads();   // barrier 1: A + B tiles visible

        // ---- prefetch next tile under the MFMA shadow ----
        if (kt + 1 < NKT) {
#pragma unroll
            for (int p = 0; p < 8; ++p) {
                const int c = p * 256 + tid;
                areg[p] = *(const f32x4*)(x + (size_t)(m0 + (c >> 4)) * KDIM
                                            + (kt + 1) * 64 + (c & 15) * 4);
            }
            const int kp0 = (kt + 1) * 32 + half * 16;
#pragma unroll
            for (int i = 0; i < 16; ++i) pw[i] = wpk[(kp0 + i) * NDIM + gn];
            scur = sc[((kt + 1) >> 1) * NDIM + gn];
        }

        // ---- compute: 2 ksteps x (4 A-frags, 4 B-frags, 16 MFMA) ----
#pragma unroll
        for (int ks = 0; ks < 2; ++ks) {
            f16x8 af[4], bfr[4];
#pragma unroll
            for (int mt = 0; mt < 4; ++mt)
                af[mt] = *(const f16x8*)&ldsA[(wm * 64 + mt * 16 + l15) * LDA
                                              + ks * 32 + quad * 8];
#pragma unroll
            for (int nt = 0; nt < 4; ++nt)
                bfr[nt] = *(const f16x8*)&ldsB[(ks * 512 + quad * 128 + wn * 64 + nt * 16 + l15) * 8];
#pragma unroll
            for (int mt = 0; mt < 4; ++mt)
#pragma unroll
                for (int nt = 0; nt < 4; ++nt)
                    acc[mt][nt] = __builtin_amdgcn_mfma_f32_16x16x32_f16(
                        af[mt], bfr[nt], acc[mt][nt], 0, 0, 0);
        }

        __syncthreads();   // barrier 2: LDS free for next iteration
    }

    // ---- epilogue: + bias, f32 store ----
    float bv[4];
#pragma unroll
    for (int nt = 0; nt < 4; ++nt)
        bv[nt] = bias[n0 + wn * 64 + nt * 16 + l15];
#pragma unroll
    for (int mt = 0; mt < 4; ++mt) {
        const int row = m0 + wm * 64 + mt * 16 + quad * 4;   // C/D: row = quad*4 + r, col = lane&15
#pragma unroll
        for (int nt = 0; nt < 4; ++nt) {
            const int col = n0 + wn * 64 + nt * 16 + l15;
#pragma unroll
            for (int r = 0; r < 4; ++r)
                out[(size_t)(row + r) * NDIM + col] = acc[mt][nt][r] + bv[nt];
        }
    }
}

extern "C" void kernel_launch(void* const* d_in, const int* in_sizes, int n_in,
                              void* d_out, int out_size, void* d_ws, size_t ws_size,
                              hipStream_t stream) {
    const float* x    = (const float*)d_in[0];
    const int*   wpk  = (const int*)d_in[1];
    const float* scl  = (const float*)d_in[2];
    const float* bias = (const float*)d_in[3];
    // d_in[4] = group_size (=128), baked in
    dim3 grid(NDIM / 128, MDIM / 128);   // 86 x 64
    int4_gemm<<<grid, dim3(256), 0, stream>>>(x, wpk, scl, bias, (float*)d_out);
}